// Round 7
// baseline (226.056 us; speedup 1.0000x reference)
//
#include <hip/hip_runtime.h>

#define T_SEQ 8192
#define E_DIM 1024
#define QS 36              // padded qkv row: [k 0..10][pad][q 12..22][pad][v 24..34][pad]
#define NEC 8              // E-chunks in qkv projection
#define ECOLS 128          // cols per qkv block
#define KC 64              // cols per LDS sub-chunk
#define NC4 16             // KC/4 float4-columns
#define X4ST 65            // float4 row stride in xP4 (pad -> 2-way-free)
#define RB 64              // qkv rows per block
#define JCH 64             // attn j-chunk rows
#define NSLOT 64           // part slots (max 4*ib+4 = 64)
#define RPB 512            // attn rows per block (2 rows/thread)
#define NIB (T_SEQ / RPB)  // 16
#define KVW 24             // compact LDS kv row: [k0..10,pad][v0..10,pad]
#define TR 16              // pass2 rows per block
#define LOG2E 1.4426950408889634f

__device__ __forceinline__ float2 pkfma(float2 a, float2 b, float2 c) {
    return make_float2(fmaf(a.x, b.x, c.x), fmaf(a.y, b.y, c.y));
}
__device__ __forceinline__ float2 f2(float x, float y) { return make_float2(x, y); }

// ws floats (overlaid): qkvF[T][QS] 1.18MB | wfp[E][12] 48KB |
//   region R: partQ[NEC][T][QS] 9.44MB overlaid by part[NSLOT][T][12] 25.2MB
//   (partQ dead after reduceQ; stream-ordered safe). ~26.4MB total.

// ---------------------------------------------------------------------------
// K0: pad Wf [E][11] -> [E][12] for coalesced float4 loads in pass2
// ---------------------------------------------------------------------------
__global__ __launch_bounds__(256) void prep_wf(const float* __restrict__ Wf,
                                               float* __restrict__ Wfp) {
    int id = blockIdx.x * 256 + threadIdx.x;
    if (id >= E_DIM * 12) return;
    int e = id / 12, d = id % 12;
    Wfp[id] = (d < 11) ? Wf[(size_t)e * 11 + d] : 0.f;
}

// ---------------------------------------------------------------------------
// K1: qkv projection. 1024 blocks (128 row-blocks x 8 col-chunks) = 4/CU.
// xe tile in LDS float4 layout xP4[c4][row] (2-way-free b128 reads/writes).
// Per 4-col iter: 1 ds_read_b128 + 9 s_load_dwordx4 (wave-uniform weights,
// scalar pipe, HALF the scalar ops of the float2 version) + 18 pkfma.
// ---------------------------------------------------------------------------
__global__ __launch_bounds__(256) void qkv_proj(
    const float* __restrict__ xe,
    const float* __restrict__ Wk, const float* __restrict__ bk,
    const float* __restrict__ Wq, const float* __restrict__ bq,
    const float* __restrict__ Wv, const float* __restrict__ bv,
    float* __restrict__ partQ) {
    const int row0 = blockIdx.x * RB;
    const int ec = blockIdx.y;
    const int lane = threadIdx.x & 63;
    const int wg = __builtin_amdgcn_readfirstlane(threadIdx.x >> 6);

    __shared__ float4 xP4[NC4 * X4ST];

    const float* wrow[9]; int col[9]; float bias[9]; bool live[9];
#pragma unroll
    for (int k = 0; k < 9; ++k) {
        int o = wg * 9 + k;
        const float* base; float b = 0.f; int c; bool lv = true;
        if (o < 11)      { base = Wk + (size_t)o * E_DIM;        b = bk[o];      c = o; }
        else if (o < 22) { base = Wq + (size_t)(o - 11) * E_DIM; b = bq[o - 11]; c = o + 1; }
        else if (o < 33) { base = Wv + (size_t)(o - 22) * E_DIM; b = bv[o - 22]; c = o + 2; }
        else             { base = Wk; c = (o == 33) ? 11 : (o == 34) ? 23 : 35; lv = false; }
        wrow[k] = base; col[k] = c; bias[k] = b; live[k] = lv;
    }

    float2 acc[9];
#pragma unroll
    for (int k = 0; k < 9; ++k) acc[k] = f2(0.f, 0.f);

    float4 st[4];
    // staging map: idx -> r = idx>>4 (0..63), c4 = idx&15
#define STAGE_LOAD(sub)                                                         \
    {                                                                           \
        const int cb = ec * ECOLS + (sub) * KC;                                 \
        _Pragma("unroll")                                                       \
        for (int t = 0; t < 4; ++t) {                                           \
            int idx = threadIdx.x + t * 256;                                    \
            int r = idx >> 4, c4 = idx & 15;                                    \
            st[t] = *(const float4*)(xe + (size_t)(row0 + r) * E_DIM + cb + c4 * 4); \
        }                                                                       \
    }

    STAGE_LOAD(0);
    for (int sub = 0; sub < ECOLS / KC; ++sub) {
        if (sub) __syncthreads();                 // WAR: prev compute done
#pragma unroll
        for (int t = 0; t < 4; ++t) {
            int idx = threadIdx.x + t * 256;
            int r = idx >> 4, c4 = idx & 15;
            xP4[c4 * X4ST + r] = st[t];
        }
        if (sub + 1 < ECOLS / KC) STAGE_LOAD(sub + 1);
        __syncthreads();

        const int cbase = ec * ECOLS + sub * KC;
#pragma unroll
        for (int c4 = 0; c4 < NC4; ++c4) {
            float4 xv = xP4[c4 * X4ST + lane];
            const int c = cbase + 4 * c4;
#pragma unroll
            for (int k = 0; k < 9; ++k) {
                const float4 wv = *(const float4*)(wrow[k] + c);
                acc[k] = pkfma(f2(xv.x, xv.y), f2(wv.x, wv.y), acc[k]);
                acc[k] = pkfma(f2(xv.z, xv.w), f2(wv.z, wv.w), acc[k]);
            }
        }
    }
#undef STAGE_LOAD

    float* dst = partQ + ((size_t)ec * T_SEQ + row0 + lane) * QS;
#pragma unroll
    for (int k = 0; k < 9; ++k) {
        float v = acc[k].x + acc[k].y + (ec == 0 ? bias[k] : 0.f);
        dst[col[k]] = live[k] ? v : 0.f;
    }
}

// ---------------------------------------------------------------------------
// K2: reduce NEC qkv partial chunks into dense qkvF.
// ---------------------------------------------------------------------------
__global__ __launch_bounds__(256) void reduceQ(const float* __restrict__ partQ,
                                               float* __restrict__ qkvF) {
    const size_t idx = (size_t)blockIdx.x * 256 + threadIdx.x;
    const float4* p = (const float4*)partQ;
    const size_t cs = (size_t)T_SEQ * (QS / 4);
    float4 s = make_float4(0.f, 0.f, 0.f, 0.f);
#pragma unroll
    for (int c = 0; c < NEC; ++c) {
        float4 a = p[idx + (size_t)c * cs];
        s.x += a.x; s.y += a.y; s.z += a.z; s.w += a.w;
    }
    ((float4*)qkvF)[idx] = s;
}

// ---------------------------------------------------------------------------
// K3: causal attention, balanced-pair grid. Block (ib, s), s < 4*ib+4,
// handles chunks s and 8*ib+7-s: every active block = exactly 128 j-iters.
// Inner loop batches 2 j's: all 12 ds_read_b128 issued up-front (straight-line
// code the compiler schedules as a burst), then compute both. 544 active
// blocks = 2/CU = 2 waves/SIMD; launch_bounds(256,2) = 256-reg cap.
// ---------------------------------------------------------------------------
__device__ __forceinline__ void stage_kv(const float* __restrict__ qkvF,
                                         float* kv, int j0) {
    for (int idx = threadIdx.x; idx < JCH * 6; idx += 256) {
        int row = idx / 6, f = idx % 6;
        int srcOff = f * 4 + (f >= 3 ? 12 : 0);
        float4 v = *(const float4*)(qkvF + (size_t)(j0 + row) * QS + srcOff);
        *(float4*)(kv + row * KVW + f * 4) = v;
    }
}

__device__ __forceinline__ void attn_chunk(const float* kv, int j0, int r0,
    const float4& qa0, const float4& qa1, const float4& qa2,
    const float4& qb0, const float4& qb1, const float4& qb2,
    float2& a01, float2& a23, float2& a45, float2& a67, float2& a89, float2& aXL,
    float2& b01, float2& b23, float2& b45, float2& b67, float2& b89, float2& bXL) {
#pragma unroll 2
    for (int jj = 0; jj < JCH; jj += 2) {
        const float* kp0 = kv + jj * KVW;
        const float* kp1 = kp0 + KVW;
        // --- 12 b128 loads up-front (both j's) ---
        const float4 kA0 = *(const float4*)(kp0);
        const float4 kB0 = *(const float4*)(kp0 + 4);
        const float4 kC0 = *(const float4*)(kp0 + 8);
        const float4 vA0 = *(const float4*)(kp0 + 12);
        const float4 vB0 = *(const float4*)(kp0 + 16);
        const float4 vC0 = *(const float4*)(kp0 + 20);
        const float4 kA1 = *(const float4*)(kp1);
        const float4 kB1 = *(const float4*)(kp1 + 4);
        const float4 kC1 = *(const float4*)(kp1 + 8);
        const float4 vA1 = *(const float4*)(kp1 + 12);
        const float4 vB1 = *(const float4*)(kp1 + 16);
        const float4 vC1 = *(const float4*)(kp1 + 20);

        // --- j = jj ---
        float2 sa = pkfma(f2(qa0.x, qa0.y), f2(kA0.x, kA0.y),
                    pkfma(f2(qa0.z, qa0.w), f2(kA0.z, kA0.w),
                    pkfma(f2(qa1.x, qa1.y), f2(kB0.x, kB0.y),
                    pkfma(f2(qa1.z, qa1.w), f2(kB0.z, kB0.w),
                    pkfma(f2(qa2.x, qa2.y), f2(kC0.x, kC0.y), f2(0.f, 0.f))))));
        float2 sb = pkfma(f2(qb0.x, qb0.y), f2(kA0.x, kA0.y),
                    pkfma(f2(qb0.z, qb0.w), f2(kA0.z, kA0.w),
                    pkfma(f2(qb1.x, qb1.y), f2(kB0.x, kB0.y),
                    pkfma(f2(qb1.z, qb1.w), f2(kB0.z, kB0.w),
                    pkfma(f2(qb2.x, qb2.y), f2(kC0.x, kC0.y), f2(0.f, 0.f))))));
        float pa = exp2f(sa.x + sa.y + qa2.z * kC0.z);
        float pb = exp2f(sb.x + sb.y + qb2.z * kC0.z);
        int j = j0 + jj;
        pa = (j <= r0)     ? pa : 0.f;
        pb = (j <= r0 + 1) ? pb : 0.f;
        float2 pa2 = f2(pa, pa), pb2 = f2(pb, pb);
        a01 = pkfma(pa2, f2(vA0.x, vA0.y), a01);
        a23 = pkfma(pa2, f2(vA0.z, vA0.w), a23);
        a45 = pkfma(pa2, f2(vB0.x, vB0.y), a45);
        a67 = pkfma(pa2, f2(vB0.z, vB0.w), a67);
        a89 = pkfma(pa2, f2(vC0.x, vC0.y), a89);
        aXL = pkfma(pa2, f2(vC0.z, 1.f),  aXL);
        b01 = pkfma(pb2, f2(vA0.x, vA0.y), b01);
        b23 = pkfma(pb2, f2(vA0.z, vA0.w), b23);
        b45 = pkfma(pb2, f2(vB0.x, vB0.y), b45);
        b67 = pkfma(pb2, f2(vB0.z, vB0.w), b67);
        b89 = pkfma(pb2, f2(vC0.x, vC0.y), b89);
        bXL = pkfma(pb2, f2(vC0.z, 1.f),  bXL);

        // --- j = jj + 1 ---
        sa = pkfma(f2(qa0.x, qa0.y), f2(kA1.x, kA1.y),
             pkfma(f2(qa0.z, qa0.w), f2(kA1.z, kA1.w),
             pkfma(f2(qa1.x, qa1.y), f2(kB1.x, kB1.y),
             pkfma(f2(qa1.z, qa1.w), f2(kB1.z, kB1.w),
             pkfma(f2(qa2.x, qa2.y), f2(kC1.x, kC1.y), f2(0.f, 0.f))))));
        sb = pkfma(f2(qb0.x, qb0.y), f2(kA1.x, kA1.y),
             pkfma(f2(qb0.z, qb0.w), f2(kA1.z, kA1.w),
             pkfma(f2(qb1.x, qb1.y), f2(kB1.x, kB1.y),
             pkfma(f2(qb1.z, qb1.w), f2(kB1.z, kB1.w),
             pkfma(f2(qb2.x, qb2.y), f2(kC1.x, kC1.y), f2(0.f, 0.f))))));
        pa = exp2f(sa.x + sa.y + qa2.z * kC1.z);
        pb = exp2f(sb.x + sb.y + qb2.z * kC1.z);
        j = j0 + jj + 1;
        pa = (j <= r0)     ? pa : 0.f;
        pb = (j <= r0 + 1) ? pb : 0.f;
        pa2 = f2(pa, pa); pb2 = f2(pb, pb);
        a01 = pkfma(pa2, f2(vA1.x, vA1.y), a01);
        a23 = pkfma(pa2, f2(vA1.z, vA1.w), a23);
        a45 = pkfma(pa2, f2(vB1.x, vB1.y), a45);
        a67 = pkfma(pa2, f2(vB1.z, vB1.w), a67);
        a89 = pkfma(pa2, f2(vC1.x, vC1.y), a89);
        aXL = pkfma(pa2, f2(vC1.z, 1.f),  aXL);
        b01 = pkfma(pb2, f2(vA1.x, vA1.y), b01);
        b23 = pkfma(pb2, f2(vA1.z, vA1.w), b23);
        b45 = pkfma(pb2, f2(vB1.x, vB1.y), b45);
        b67 = pkfma(pb2, f2(vB1.z, vB1.w), b67);
        b89 = pkfma(pb2, f2(vC1.x, vC1.y), b89);
        bXL = pkfma(pb2, f2(vC1.z, 1.f),  bXL);
    }
}

__global__ __launch_bounds__(256, 2) void attn(const float* __restrict__ qkvF,
                                               float* __restrict__ part) {
    const int ib = blockIdx.x, s = blockIdx.y;
    if (s >= 4 * ib + 4) return;                  // 544 active blocks, uniform work
    const int row0 = ib * RPB;
    const int r0 = row0 + threadIdx.x * 2;

    const float* qp0 = qkvF + (size_t)r0 * QS + 12;
    const float* qp1 = qp0 + QS;
    float4 qa0 = *(const float4*)(qp0), qa1 = *(const float4*)(qp0 + 4), qa2 = *(const float4*)(qp0 + 8);
    float4 qb0 = *(const float4*)(qp1), qb1 = *(const float4*)(qp1 + 4), qb2 = *(const float4*)(qp1 + 8);
    qa0.x *= LOG2E; qa0.y *= LOG2E; qa0.z *= LOG2E; qa0.w *= LOG2E;
    qa1.x *= LOG2E; qa1.y *= LOG2E; qa1.z *= LOG2E; qa1.w *= LOG2E;
    qa2.x *= LOG2E; qa2.y *= LOG2E; qa2.z *= LOG2E;
    qb0.x *= LOG2E; qb0.y *= LOG2E; qb0.z *= LOG2E; qb0.w *= LOG2E;
    qb1.x *= LOG2E; qb1.y *= LOG2E; qb1.z *= LOG2E; qb1.w *= LOG2E;
    qb2.x *= LOG2E; qb2.y *= LOG2E; qb2.z *= LOG2E;

    float2 a01 = f2(0.f, 0.f), a23 = a01, a45 = a01, a67 = a01, a89 = a01, aXL = a01;
    float2 b01 = a01, b23 = a01, b45 = a01, b67 = a01, b89 = a01, bXL = a01;

    __shared__ float kv[JCH * KVW];

#pragma unroll
    for (int pass = 0; pass < 2; ++pass) {
        const int jc = pass ? (8 * ib + 7 - s) : s;
        const int j0 = jc * JCH;
        if (pass) __syncthreads();                // WAR on kv
        stage_kv(qkvF, kv, j0);
        __syncthreads();
        attn_chunk(kv, j0, r0, qa0, qa1, qa2, qb0, qb1, qb2,
                   a01, a23, a45, a67, a89, aXL, b01, b23, b45, b67, b89, bXL);
    }

    float* dst = part + ((size_t)s * T_SEQ + r0) * 12;
    float4 t;
    t.x = a01.x; t.y = a01.y; t.z = a23.x; t.w = a23.y; *(float4*)(dst + 0)  = t;
    t.x = a45.x; t.y = a45.y; t.z = a67.x; t.w = a67.y; *(float4*)(dst + 4)  = t;
    t.x = a89.x; t.y = a89.y; t.z = aXL.x; t.w = aXL.y; *(float4*)(dst + 8)  = t;
    t.x = b01.x; t.y = b01.y; t.z = b23.x; t.w = b23.y; *(float4*)(dst + 12) = t;
    t.x = b45.x; t.y = b45.y; t.z = b67.x; t.w = b67.y; *(float4*)(dst + 16) = t;
    t.x = b89.x; t.y = b89.y; t.z = bXL.x; t.w = bXL.y; *(float4*)(dst + 20) = t;
}

// ---------------------------------------------------------------------------
// K4: fused partial-reduce + normalize + output GEMM + bias.
// Slot count per row-block ib is 4*ib+4 (balanced-pair scheme).
// ---------------------------------------------------------------------------
__global__ __launch_bounds__(256) void pass2(const float* __restrict__ part,
                                             const float* __restrict__ Wfp,
                                             const float* __restrict__ bf,
                                             float* __restrict__ out) {
    const int t0 = blockIdx.x * TR;
    __shared__ float res[TR][12];
    const int cnt = 4 * (t0 / RPB) + 4;           // uniform per block, <= 64
    if (threadIdx.x < TR * 12) {
        const float* p = part + (size_t)t0 * 12 + threadIdx.x;
        const size_t S = (size_t)T_SEQ * 12;
        float v[4];
#pragma unroll
        for (int u = 0; u < 4; ++u) v[u] = 0.f;
        for (int c = 0; c < cnt; c += 4) {
#pragma unroll
            for (int u = 0; u < 4; ++u) v[u] += p[(size_t)(c + u) * S];
        }
        float sum = (v[0] + v[1]) + (v[2] + v[3]);
        const int d = threadIdx.x % 12;
        res[threadIdx.x / 12][d] = (d == 11) ? (1.f / sum) : sum;
    }
    __syncthreads();

    const int e0 = threadIdx.x * 4;
    float4 wf[4][3];
#pragma unroll
    for (int ee = 0; ee < 4; ++ee) {
        const float4* wp = (const float4*)(Wfp + (size_t)(e0 + ee) * 12);
        wf[ee][0] = wp[0]; wf[ee][1] = wp[1]; wf[ee][2] = wp[2];
    }
    const float4 bv = *(const float4*)(bf + e0);

    for (int r = 0; r < TR; ++r) {
        float rr[12];
#pragma unroll
        for (int d = 0; d < 12; ++d) rr[d] = res[r][d];
        float2 a0 = f2(0.f, 0.f), a1 = a0, a2 = a0, a3 = a0;
#pragma unroll
        for (int d = 0; d < 10; d += 2) {
            float2 rv = f2(rr[d], rr[d + 1]);
            a0 = pkfma(rv, f2(((const float*)&wf[0][0])[d], ((const float*)&wf[0][0])[d + 1]), a0);
            a1 = pkfma(rv, f2(((const float*)&wf[1][0])[d], ((const float*)&wf[1][0])[d + 1]), a1);
            a2 = pkfma(rv, f2(((const float*)&wf[2][0])[d], ((const float*)&wf[2][0])[d + 1]), a2);
            a3 = pkfma(rv, f2(((const float*)&wf[3][0])[d], ((const float*)&wf[3][0])[d + 1]), a3);
        }
        const float rl = rr[11];
        float4 ov;
        ov.x = (a0.x + a0.y + rr[10] * wf[0][2].z) * rl + bv.x;
        ov.y = (a1.x + a1.y + rr[10] * wf[1][2].z) * rl + bv.y;
        ov.z = (a2.x + a2.y + rr[10] * wf[2][2].z) * rl + bv.z;
        ov.w = (a3.x + a3.y + rr[10] * wf[3][2].z) * rl + bv.w;
        *(float4*)(out + (size_t)(t0 + r) * E_DIM + e0) = ov;
    }
}

// ---------------------------------------------------------------------------
extern "C" void kernel_launch(void* const* d_in, const int* in_sizes, int n_in,
                              void* d_out, int out_size, void* d_ws, size_t ws_size,
                              hipStream_t stream) {
    const float* xe = (const float*)d_in[1];
    const float* Wk = (const float*)d_in[2];
    const float* bk = (const float*)d_in[3];
    const float* Wq = (const float*)d_in[4];
    const float* bq = (const float*)d_in[5];
    const float* Wv = (const float*)d_in[6];
    const float* bv = (const float*)d_in[7];
    const float* Wf = (const float*)d_in[8];
    const float* bf = (const float*)d_in[9];
    float* out = (float*)d_out;

    float* qkvF  = (float*)d_ws;                              // [T][QS]
    float* wfp   = qkvF + (size_t)T_SEQ * QS;                 // [E][12]
    float* partQ = wfp + (size_t)E_DIM * 12;                  // [NEC][T][QS]
    float* part  = partQ;                                     // overlay: [NSLOT][T][12]

    prep_wf<<<(E_DIM * 12 + 255) / 256, 256, 0, stream>>>(Wf, wfp);
    qkv_proj<<<dim3(T_SEQ / RB, NEC), 256, 0, stream>>>(xe, Wk, bk, Wq, bq, Wv, bv, partQ);
    reduceQ<<<(T_SEQ * (QS / 4)) / 256, 256, 0, stream>>>(partQ, qkvF);
    attn<<<dim3(NIB, NSLOT), 256, 0, stream>>>(qkvF, part);
    pass2<<<T_SEQ / TR, 256, 0, stream>>>(part, wfp, bf, out);
}

// Round 8
// 193.978 us; speedup vs baseline: 1.1654x; 1.1654x over previous
//
#include <hip/hip_runtime.h>

#define T_SEQ 8192
#define E_DIM 1024
#define QS 36              // padded qkv row: [k 0..10][pad][q 12..22][pad][v 24..34][pad]
#define NEC 8              // E-chunks in qkv projection
#define ECOLS 128          // cols per qkv block
#define NC4 32             // ECOLS/4 float4-columns
#define X4ST 33            // float4 row stride in xT (33*16B -> 8-phase conflict-free b128)
#define RB 64              // qkv rows per block
#define RPB 512            // attn rows per block (2 rows/thread)
#define NIB (T_SEQ / RPB)  // 16
#define KVW 24             // compact LDS kv row: [k0..10,pad][v0..10,pad]
#define TR 16              // pass2 rows per block
#define LOG2E 1.4426950408889634f

__device__ __forceinline__ float2 pkfma(float2 a, float2 b, float2 c) {
    return make_float2(fmaf(a.x, b.x, c.x), fmaf(a.y, b.y, c.y));
}
__device__ __forceinline__ float2 f2(float x, float y) { return make_float2(x, y); }

// ws floats (overlaid): qkvF[T][QS] 1.18MB | wfp[E][12] 48KB |
//   region R: partQ[NEC][T][QS] 9.44MB overlaid by part[NSLOT][T][12]
//   NSLOT = 128 (50.3MB) if ws allows, else 64 (25.2MB).

// ---------------------------------------------------------------------------
// K0: pad Wf [E][11] -> [E][12] for coalesced float4 loads in pass2
// ---------------------------------------------------------------------------
__global__ __launch_bounds__(256) void prep_wf(const float* __restrict__ Wf,
                                               float* __restrict__ Wfp) {
    int id = blockIdx.x * 256 + threadIdx.x;
    if (id >= E_DIM * 12) return;
    int e = id / 12, d = id % 12;
    Wfp[id] = (d < 11) ? Wf[(size_t)e * 11 + d] : 0.f;
}

// ---------------------------------------------------------------------------
// K1: qkv projection, NO scalar-pipe weight stream (R7 lesson: s_load weights
// thrash the shared scalar K$ -> all pipes idle). Both operands come from LDS:
//   xT[64][33 f4]  xe tile, per-lane b128 reads (stride-33 -> 8-phase clean)
//   wT[36][32 f4]  weight tile, wave-uniform broadcast b128 reads
// One global->LDS stage + one barrier, then 32 straight c4 iterations.
// LDS 52.2KB -> 3 blocks/CU. 1024 blocks (128 row-blocks x 8 col-chunks).
// ---------------------------------------------------------------------------
__global__ __launch_bounds__(256) void qkv_proj(
    const float* __restrict__ xe,
    const float* __restrict__ Wk, const float* __restrict__ bk,
    const float* __restrict__ Wq, const float* __restrict__ bq,
    const float* __restrict__ Wv, const float* __restrict__ bv,
    float* __restrict__ partQ) {
    const int row0 = blockIdx.x * RB;
    const int ec = blockIdx.y;
    const int lane = threadIdx.x & 63;
    const int wg = threadIdx.x >> 6;
    const int cb = ec * ECOLS;

    __shared__ float4 xT[RB * X4ST];      // 33.8 KB
    __shared__ float4 wT[36 * NC4];       // 18.4 KB

    // ---- stage xe tile: 2048 f4, 8 per thread, coalesced ----
#pragma unroll
    for (int t = 0; t < 8; ++t) {
        int idx = threadIdx.x + t * 256;
        int r = idx >> 5, c4 = idx & 31;
        xT[r * X4ST + c4] =
            *(const float4*)(xe + (size_t)(row0 + r) * E_DIM + cb + c4 * 4);
    }
    // ---- stage W tile: 36 rows x 32 f4 (rows 33..35 zero) ----
    for (int idx = threadIdx.x; idx < 36 * NC4; idx += 256) {
        int r = idx >> 5, c4 = idx & 31;
        float4 v = make_float4(0.f, 0.f, 0.f, 0.f);
        if (r < 33) {
            const float* base = (r < 11) ? (Wk + (size_t)r * E_DIM)
                              : (r < 22) ? (Wq + (size_t)(r - 11) * E_DIM)
                                         : (Wv + (size_t)(r - 22) * E_DIM);
            v = *(const float4*)(base + cb + c4 * 4);
        }
        wT[idx] = v;
    }
    __syncthreads();

    float2 acc[9];
#pragma unroll
    for (int k = 0; k < 9; ++k) acc[k] = f2(0.f, 0.f);

    const float4* xr = xT + lane * X4ST;
    const float4* wr = wT + wg * 9 * NC4;
#pragma unroll 4
    for (int c4 = 0; c4 < NC4; ++c4) {
        float4 xv = xr[c4];
        float2 xlo = f2(xv.x, xv.y), xhi = f2(xv.z, xv.w);
#pragma unroll
        for (int k = 0; k < 9; ++k) {
            float4 wv = wr[k * NC4 + c4];          // broadcast
            acc[k] = pkfma(xlo, f2(wv.x, wv.y), acc[k]);
            acc[k] = pkfma(xhi, f2(wv.z, wv.w), acc[k]);
        }
    }

    float* dst = partQ + ((size_t)ec * T_SEQ + row0 + lane) * QS;
#pragma unroll
    for (int k = 0; k < 9; ++k) {
        int o = wg * 9 + k;
        bool live = (o < 33);
        int c = (o < 11) ? o : (o < 22) ? o + 1 : (o < 33) ? o + 2
                : (o == 33) ? 11 : (o == 34) ? 23 : 35;
        float b = 0.f;
        if (ec == 0 && live)
            b = (o < 11) ? bk[o] : (o < 22) ? bq[o - 11] : bv[o - 22];
        dst[c] = live ? (acc[k].x + acc[k].y + b) : 0.f;
    }
}

// ---------------------------------------------------------------------------
// K2: reduce NEC qkv partial chunks into dense qkvF.
// ---------------------------------------------------------------------------
__global__ __launch_bounds__(256) void reduceQ(const float* __restrict__ partQ,
                                               float* __restrict__ qkvF) {
    const size_t idx = (size_t)blockIdx.x * 256 + threadIdx.x;
    const float4* p = (const float4*)partQ;
    const size_t cs = (size_t)T_SEQ * (QS / 4);
    float4 s = make_float4(0.f, 0.f, 0.f, 0.f);
#pragma unroll
    for (int c = 0; c < NEC; ++c) {
        float4 a = p[idx + (size_t)c * cs];
        s.x += a.x; s.y += a.y; s.z += a.z; s.w += a.w;
    }
    ((float4*)qkvF)[idx] = s;
}

// ---------------------------------------------------------------------------
// K3: causal attention, live-only flattened grid of balanced pairs.
// Template LJCH (j-chunk rows), H (blocks per ib = H*(ib+1)).
// Block b -> (ib, s): prefix = H*ib*(ib+1)/2; chunks per ib = 2H*(ib+1);
// block does chunks s and 2H*(ib+1)-1-s  -> exactly 2*LJCH j-iters each.
// H=8/LJCH=32: 1088 live blocks (~17 waves/CU). H=4/LJCH=64: 544 (R6 cfg).
// ---------------------------------------------------------------------------
template <int LJCH>
__device__ __forceinline__ void stage_kv(const float* __restrict__ qkvF,
                                         float* kv, int j0) {
    for (int idx = threadIdx.x; idx < LJCH * 6; idx += 256) {
        int row = idx / 6, f = idx % 6;
        int srcOff = f * 4 + (f >= 3 ? 12 : 0);
        float4 v = *(const float4*)(qkvF + (size_t)(j0 + row) * QS + srcOff);
        *(float4*)(kv + row * KVW + f * 4) = v;
    }
}

template <int LJCH>
__device__ __forceinline__ void attn_chunk(const float* kv, int j0, int r0,
    const float4& qa0, const float4& qa1, const float4& qa2,
    const float4& qb0, const float4& qb1, const float4& qb2,
    float2& a01, float2& a23, float2& a45, float2& a67, float2& a89, float2& aXL,
    float2& b01, float2& b23, float2& b45, float2& b67, float2& b89, float2& bXL) {
#pragma unroll 2
    for (int jj = 0; jj < LJCH; ++jj) {
        const float* kp = kv + jj * KVW;
        const float4 kA = *(const float4*)(kp);
        const float4 kB = *(const float4*)(kp + 4);
        const float4 kC = *(const float4*)(kp + 8);
        const float4 vA = *(const float4*)(kp + 12);
        const float4 vB = *(const float4*)(kp + 16);
        const float4 vC = *(const float4*)(kp + 20);

        float2 sa = pkfma(f2(qa0.x, qa0.y), f2(kA.x, kA.y),
                    pkfma(f2(qa0.z, qa0.w), f2(kA.z, kA.w),
                    pkfma(f2(qa1.x, qa1.y), f2(kB.x, kB.y),
                    pkfma(f2(qa1.z, qa1.w), f2(kB.z, kB.w),
                    pkfma(f2(qa2.x, qa2.y), f2(kC.x, kC.y), f2(0.f, 0.f))))));
        float2 sb = pkfma(f2(qb0.x, qb0.y), f2(kA.x, kA.y),
                    pkfma(f2(qb0.z, qb0.w), f2(kA.z, kA.w),
                    pkfma(f2(qb1.x, qb1.y), f2(kB.x, kB.y),
                    pkfma(f2(qb1.z, qb1.w), f2(kB.z, kB.w),
                    pkfma(f2(qb2.x, qb2.y), f2(kC.x, kC.y), f2(0.f, 0.f))))));
        float pa = exp2f(sa.x + sa.y + qa2.z * kC.z);
        float pb = exp2f(sb.x + sb.y + qb2.z * kC.z);
        const int j = j0 + jj;
        pa = (j <= r0)     ? pa : 0.f;
        pb = (j <= r0 + 1) ? pb : 0.f;
        float2 pa2 = f2(pa, pa), pb2 = f2(pb, pb);
        a01 = pkfma(pa2, f2(vA.x, vA.y), a01);
        a23 = pkfma(pa2, f2(vA.z, vA.w), a23);
        a45 = pkfma(pa2, f2(vB.x, vB.y), a45);
        a67 = pkfma(pa2, f2(vB.z, vB.w), a67);
        a89 = pkfma(pa2, f2(vC.x, vC.y), a89);
        aXL = pkfma(pa2, f2(vC.z, 1.f),  aXL);
        b01 = pkfma(pb2, f2(vA.x, vA.y), b01);
        b23 = pkfma(pb2, f2(vA.z, vA.w), b23);
        b45 = pkfma(pb2, f2(vB.x, vB.y), b45);
        b67 = pkfma(pb2, f2(vB.z, vB.w), b67);
        b89 = pkfma(pb2, f2(vC.x, vC.y), b89);
        bXL = pkfma(pb2, f2(vC.z, 1.f),  bXL);
    }
}

template <int LJCH, int H>
__global__ __launch_bounds__(256, 4) void attn(const float* __restrict__ qkvF,
                                               float* __restrict__ part) {
    const int b = blockIdx.x;
    int ib = (int)((sqrtf((float)(8 * b / H + 1)) - 1.0f) * 0.5f);
    while (H * (ib + 1) * (ib + 2) / 2 <= b) ++ib;
    while (H * ib * (ib + 1) / 2 > b) --ib;
    const int s = b - H * ib * (ib + 1) / 2;
    const int chunkB = 2 * H * (ib + 1) - 1 - s;

    const int row0 = ib * RPB;
    const int r0 = row0 + threadIdx.x * 2;

    const float* qp0 = qkvF + (size_t)r0 * QS + 12;
    const float* qp1 = qp0 + QS;
    float4 qa0 = *(const float4*)(qp0), qa1 = *(const float4*)(qp0 + 4), qa2 = *(const float4*)(qp0 + 8);
    float4 qb0 = *(const float4*)(qp1), qb1 = *(const float4*)(qp1 + 4), qb2 = *(const float4*)(qp1 + 8);
    qa0.x *= LOG2E; qa0.y *= LOG2E; qa0.z *= LOG2E; qa0.w *= LOG2E;
    qa1.x *= LOG2E; qa1.y *= LOG2E; qa1.z *= LOG2E; qa1.w *= LOG2E;
    qa2.x *= LOG2E; qa2.y *= LOG2E; qa2.z *= LOG2E;
    qb0.x *= LOG2E; qb0.y *= LOG2E; qb0.z *= LOG2E; qb0.w *= LOG2E;
    qb1.x *= LOG2E; qb1.y *= LOG2E; qb1.z *= LOG2E; qb1.w *= LOG2E;
    qb2.x *= LOG2E; qb2.y *= LOG2E; qb2.z *= LOG2E;

    float2 a01 = f2(0.f, 0.f), a23 = a01, a45 = a01, a67 = a01, a89 = a01, aXL = a01;
    float2 b01 = a01, b23 = a01, b45 = a01, b67 = a01, b89 = a01, bXL = a01;

    __shared__ float kv[LJCH * KVW];

#pragma unroll
    for (int pass = 0; pass < 2; ++pass) {
        const int jc = pass ? chunkB : s;
        const int j0 = jc * LJCH;
        if (pass) __syncthreads();                // WAR on kv
        stage_kv<LJCH>(qkvF, kv, j0);
        __syncthreads();
        attn_chunk<LJCH>(kv, j0, r0, qa0, qa1, qa2, qb0, qb1, qb2,
                         a01, a23, a45, a67, a89, aXL, b01, b23, b45, b67, b89, bXL);
    }

    float* dst = part + ((size_t)s * T_SEQ + r0) * 12;
    float4 t;
    t.x = a01.x; t.y = a01.y; t.z = a23.x; t.w = a23.y; *(float4*)(dst + 0)  = t;
    t.x = a45.x; t.y = a45.y; t.z = a67.x; t.w = a67.y; *(float4*)(dst + 4)  = t;
    t.x = a89.x; t.y = a89.y; t.z = aXL.x; t.w = aXL.y; *(float4*)(dst + 8)  = t;
    t.x = b01.x; t.y = b01.y; t.z = b23.x; t.w = b23.y; *(float4*)(dst + 12) = t;
    t.x = b45.x; t.y = b45.y; t.z = b67.x; t.w = b67.y; *(float4*)(dst + 16) = t;
    t.x = b89.x; t.y = b89.y; t.z = bXL.x; t.w = bXL.y; *(float4*)(dst + 20) = t;
}

// ---------------------------------------------------------------------------
// K4: fused partial-reduce + normalize + output GEMM + bias.
// Slot count per row-block = H*(t0/RPB) + H (balanced-pair scheme).
// ---------------------------------------------------------------------------
__global__ __launch_bounds__(256) void pass2(const float* __restrict__ part,
                                             const float* __restrict__ Wfp,
                                             const float* __restrict__ bf,
                                             float* __restrict__ out, int H) {
    const int t0 = blockIdx.x * TR;
    __shared__ float res[TR][12];
    const int cnt = H * (t0 / RPB) + H;           // uniform per block
    if (threadIdx.x < TR * 12) {
        const float* p = part + (size_t)t0 * 12 + threadIdx.x;
        const size_t S = (size_t)T_SEQ * 12;
        float v[4];
#pragma unroll
        for (int u = 0; u < 4; ++u) v[u] = 0.f;
        for (int c = 0; c < cnt; c += 4) {
#pragma unroll
            for (int u = 0; u < 4; ++u) v[u] += p[(size_t)(c + u) * S];
        }
        float sum = (v[0] + v[1]) + (v[2] + v[3]);
        const int d = threadIdx.x % 12;
        res[threadIdx.x / 12][d] = (d == 11) ? (1.f / sum) : sum;
    }
    __syncthreads();

    const int e0 = threadIdx.x * 4;
    float4 wf[4][3];
#pragma unroll
    for (int ee = 0; ee < 4; ++ee) {
        const float4* wp = (const float4*)(Wfp + (size_t)(e0 + ee) * 12);
        wf[ee][0] = wp[0]; wf[ee][1] = wp[1]; wf[ee][2] = wp[2];
    }
    const float4 bv = *(const float4*)(bf + e0);

    for (int r = 0; r < TR; ++r) {
        float rr[12];
#pragma unroll
        for (int d = 0; d < 12; ++d) rr[d] = res[r][d];
        float2 a0 = f2(0.f, 0.f), a1 = a0, a2 = a0, a3 = a0;
#pragma unroll
        for (int d = 0; d < 10; d += 2) {
            float2 rv = f2(rr[d], rr[d + 1]);
            a0 = pkfma(rv, f2(((const float*)&wf[0][0])[d], ((const float*)&wf[0][0])[d + 1]), a0);
            a1 = pkfma(rv, f2(((const float*)&wf[1][0])[d], ((const float*)&wf[1][0])[d + 1]), a1);
            a2 = pkfma(rv, f2(((const float*)&wf[2][0])[d], ((const float*)&wf[2][0])[d + 1]), a2);
            a3 = pkfma(rv, f2(((const float*)&wf[3][0])[d], ((const float*)&wf[3][0])[d + 1]), a3);
        }
        const float rl = rr[11];
        float4 ov;
        ov.x = (a0.x + a0.y + rr[10] * wf[0][2].z) * rl + bv.x;
        ov.y = (a1.x + a1.y + rr[10] * wf[1][2].z) * rl + bv.y;
        ov.z = (a2.x + a2.y + rr[10] * wf[2][2].z) * rl + bv.z;
        ov.w = (a3.x + a3.y + rr[10] * wf[3][2].z) * rl + bv.w;
        *(float4*)(out + (size_t)(t0 + r) * E_DIM + e0) = ov;
    }
}

// ---------------------------------------------------------------------------
extern "C" void kernel_launch(void* const* d_in, const int* in_sizes, int n_in,
                              void* d_out, int out_size, void* d_ws, size_t ws_size,
                              hipStream_t stream) {
    const float* xe = (const float*)d_in[1];
    const float* Wk = (const float*)d_in[2];
    const float* bk = (const float*)d_in[3];
    const float* Wq = (const float*)d_in[4];
    const float* bq = (const float*)d_in[5];
    const float* Wv = (const float*)d_in[6];
    const float* bv = (const float*)d_in[7];
    const float* Wf = (const float*)d_in[8];
    const float* bf = (const float*)d_in[9];
    float* out = (float*)d_out;

    float* qkvF  = (float*)d_ws;                              // [T][QS]
    float* wfp   = qkvF + (size_t)T_SEQ * QS;                 // [E][12]
    float* partQ = wfp + (size_t)E_DIM * 12;                  // [NEC][T][QS]
    float* part  = partQ;                                     // overlay

    const size_t fixed = ((size_t)T_SEQ * QS + (size_t)E_DIM * 12) * 4;
    const size_t need32 = fixed + (size_t)128 * T_SEQ * 12 * 4;   // ~51.6 MB

    prep_wf<<<(E_DIM * 12 + 255) / 256, 256, 0, stream>>>(Wf, wfp);
    qkv_proj<<<dim3(T_SEQ / RB, NEC), 256, 0, stream>>>(xe, Wk, bk, Wq, bq, Wv, bv, partQ);
    reduceQ<<<(T_SEQ * (QS / 4)) / 256, 256, 0, stream>>>(partQ, qkvF);

    if (ws_size >= need32) {
        // H=8, LJCH=32: 1088 live blocks, 128 part slots
        attn<32, 8><<<8 * NIB * (NIB + 1) / 2, 256, 0, stream>>>(qkvF, part);
        pass2<<<T_SEQ / TR, 256, 0, stream>>>(part, wfp, bf, out, 8);
    } else {
        // H=4, LJCH=64: 544 live blocks, 64 part slots (proven footprint)
        attn<64, 4><<<4 * NIB * (NIB + 1) / 2, 256, 0, stream>>>(qkvF, part);
        pass2<<<T_SEQ / TR, 256, 0, stream>>>(part, wfp, bf, out, 4);
    }
}